// Round 2
// baseline (3850.572 us; speedup 1.0000x reference)
//
#include <hip/hip_runtime.h>
#include <stdint.h>
#include <stddef.h>

#define NB   16
#define CIN  512
#define COUT 512
#define KK   1024
#define HH   64
#define WW   64
#define NP   (NB*HH*WW)      // 65536 positions

// ---------------- threefry2x32 (JAX-compatible, 20 rounds) ----------------
__host__ __device__ inline void tf2x32(uint32_t k0, uint32_t k1,
                                       uint32_t x0, uint32_t x1,
                                       uint32_t& o0, uint32_t& o1) {
  uint32_t ks2 = k0 ^ k1 ^ 0x1BD11BDAu;
  x0 += k0; x1 += k1;
#define TF_RND(r) { x0 += x1; x1 = (x1 << r) | (x1 >> (32 - r)); x1 ^= x0; }
  TF_RND(13) TF_RND(15) TF_RND(26) TF_RND(6)
  x0 += k1;  x1 += ks2 + 1u;
  TF_RND(17) TF_RND(29) TF_RND(16) TF_RND(24)
  x0 += ks2; x1 += k0 + 2u;
  TF_RND(13) TF_RND(15) TF_RND(26) TF_RND(6)
  x0 += k0;  x1 += k1 + 3u;
  TF_RND(17) TF_RND(29) TF_RND(16) TF_RND(24)
  x0 += k1;  x1 += ks2 + 4u;
  TF_RND(13) TF_RND(15) TF_RND(26) TF_RND(6)
  x0 += ks2; x1 += k0 + 5u;
#undef TF_RND
  o0 = x0; o1 = x1;
}

__device__ inline float bits_to_u(uint32_t b) {
  // JAX f32 uniform in [0,1): bitcast((b>>9)|0x3f800000) - 1.0f
  return __uint_as_float((b >> 9) | 0x3f800000u) - 1.0f;
}

// ---------------- kmatT = (codebook @ wk^T)^T, v = codebook @ wv^T ----------------
__global__ __launch_bounds__(256) void k_kmv(const float* __restrict__ cb,
                                             const float* __restrict__ wk,
                                             const float* __restrict__ wv,
                                             float* __restrict__ kmatT,
                                             float* __restrict__ v) {
  __shared__ __align__(16) float row[CIN];
  const int k = blockIdx.x;
  const int t = threadIdx.x;
  const float* cr = cb + (size_t)k * CIN;
  for (int c = t; c < CIN; c += 256) row[c] = cr[c];
  __syncthreads();
#pragma unroll
  for (int oo = 0; oo < 2; ++oo) {
    const int o = t + oo * 256;
    const float* kr = wk + (size_t)o * CIN;
    const float* vr = wv + (size_t)o * CIN;
    double ak = 0.0, av = 0.0;
    for (int c = 0; c < CIN; c += 4) {
      float4 c4 = *(const float4*)&row[c];
      float4 k4 = *(const float4*)(kr + c);
      float4 v4 = *(const float4*)(vr + c);
      ak += (double)c4.x * (double)k4.x; av += (double)c4.x * (double)v4.x;
      ak += (double)c4.y * (double)k4.y; av += (double)c4.y * (double)v4.y;
      ak += (double)c4.z * (double)k4.z; av += (double)c4.z * (double)v4.z;
      ak += (double)c4.w * (double)k4.w; av += (double)c4.w * (double)v4.w;
    }
    kmatT[(size_t)o * KK + k]   = (float)ak;
    v[(size_t)k * COUT + o]     = (float)av;
  }
}

// ---------------- q[p][o] = sum_c latent[n,c,h,w] * wq[o,c]  (f64 accum) ----------------
__global__ __launch_bounds__(256) void k_q(const float* __restrict__ latent,
                                           const float* __restrict__ wq,
                                           float* __restrict__ q) {
  __shared__ double As[16][64];    // [c][w]
  __shared__ double Bs[16][128];   // [c][o]
  const int t  = threadIdx.x;
  const int ob = blockIdx.x & 3;          // o-tile of 128
  const int rb = blockIdx.x >> 2;         // (n,h)
  const int n  = rb >> 6, h = rb & 63;
  const int wt = (t & 15) * 4;            // 4 w's
  const int ot = (t >> 4) * 8;            // 8 o's

  double acc[4][8];
#pragma unroll
  for (int i = 0; i < 4; ++i)
#pragma unroll
    for (int j = 0; j < 8; ++j) acc[i][j] = 0.0;

  const float* Ab = latent + (size_t)n * CIN * 4096 + h * 64;
  const float* Bb = wq + (size_t)(ob * 128) * CIN;

  for (int c0 = 0; c0 < CIN; c0 += 16) {
    {
      const int c2 = t >> 4, w4 = (t & 15) * 4;
      float4 f = *(const float4*)(Ab + (size_t)(c0 + c2) * 4096 + w4);
      As[c2][w4+0] = f.x; As[c2][w4+1] = f.y; As[c2][w4+2] = f.z; As[c2][w4+3] = f.w;
    }
    {
      const int o = t >> 1, c8 = (t & 1) * 8;
      const float* src = Bb + (size_t)o * CIN + c0 + c8;
      float4 f0 = *(const float4*)src;
      float4 f1 = *(const float4*)(src + 4);
      Bs[c8+0][o] = f0.x; Bs[c8+1][o] = f0.y; Bs[c8+2][o] = f0.z; Bs[c8+3][o] = f0.w;
      Bs[c8+4][o] = f1.x; Bs[c8+5][o] = f1.y; Bs[c8+6][o] = f1.z; Bs[c8+7][o] = f1.w;
    }
    __syncthreads();
#pragma unroll 4
    for (int c2 = 0; c2 < 16; ++c2) {
      double a[4], b[8];
#pragma unroll
      for (int i = 0; i < 4; ++i) a[i] = As[c2][wt + i];
#pragma unroll
      for (int j = 0; j < 8; ++j) b[j] = Bs[c2][ot + j];
#pragma unroll
      for (int i = 0; i < 4; ++i)
#pragma unroll
        for (int j = 0; j < 8; ++j) acc[i][j] += a[i] * b[j];
    }
    __syncthreads();
  }
#pragma unroll
  for (int i = 0; i < 4; ++i) {
    size_t p = (size_t)rb * 64 + wt + i;
    float* dst = q + p * COUT + ob * 128 + ot;
#pragma unroll
    for (int j = 0; j < 8; ++j) dst[j] = (float)acc[i][j];
  }
}

// ---------------- logit GEMM (f64 accum) + fused argmax/trueCode/binCount ----------------
__global__ __launch_bounds__(256) void k_logit(const float* __restrict__ q,
                                               const float* __restrict__ kmatT,
                                               float* __restrict__ out_logit,
                                               int* __restrict__ trueCode,
                                               int* __restrict__ binCnt) {
  __shared__ double qs[32][16];     // [pp][o2]
  __shared__ double ksd[16][256];   // [o2][k within kc-tile]

  const int t = threadIdx.x;
  const int w = t >> 6, l = t & 63;
  const int pbase = blockIdx.x * 32;

  double best[8]; int bk[8];
#pragma unroll
  for (int i = 0; i < 8; ++i) { best[i] = -1.0e300; bk[i] = 0; }

  for (int kc = 0; kc < 4; ++kc) {
    double acc[8][4];
#pragma unroll
    for (int i = 0; i < 8; ++i)
#pragma unroll
      for (int j = 0; j < 4; ++j) acc[i][j] = 0.0;

    for (int oc = 0; oc < 32; ++oc) {
      if (t < 128) {
        const int pp = t >> 2, o4 = (t & 3) * 4;
        float4 f = *(const float4*)&q[(size_t)(pbase + pp) * COUT + oc * 16 + o4];
        qs[pp][o4+0] = f.x; qs[pp][o4+1] = f.y; qs[pp][o4+2] = f.z; qs[pp][o4+3] = f.w;
      }
      {
        const int o2 = t >> 4, kb = (t & 15) * 16;
        const float* src = &kmatT[(size_t)(oc * 16 + o2) * KK + kc * 256 + kb];
#pragma unroll
        for (int i = 0; i < 4; ++i) {
          float4 f = *(const float4*)(src + i * 4);
          ksd[o2][kb + i*4 + 0] = f.x; ksd[o2][kb + i*4 + 1] = f.y;
          ksd[o2][kb + i*4 + 2] = f.z; ksd[o2][kb + i*4 + 3] = f.w;
        }
      }
      __syncthreads();
#pragma unroll 4
      for (int o2 = 0; o2 < 16; ++o2) {
        const double b0 = ksd[o2][l];
        const double b1 = ksd[o2][64  + l];
        const double b2 = ksd[o2][128 + l];
        const double b3 = ksd[o2][192 + l];
#pragma unroll
        for (int pp = 0; pp < 8; ++pp) {
          const double a = qs[w * 8 + pp][o2];
          acc[pp][0] += a * b0; acc[pp][1] += a * b1;
          acc[pp][2] += a * b2; acc[pp][3] += a * b3;
        }
      }
      __syncthreads();
    }
    // emit this kc's 256 k's
#pragma unroll
    for (int pp = 0; pp < 8; ++pp) {
      const int p = pbase + w * 8 + pp;
#pragma unroll
      for (int j = 0; j < 4; ++j) {
        const int k = kc * 256 + j * 64 + l;
        const double val = acc[pp][j] / 22.627416997969522;  // / sqrt(512)
        out_logit[(size_t)p * KK + k] = (float)val;
        if (val > best[pp]) { best[pp] = val; bk[pp] = k; }
      }
    }
  }
  // per-row argmax across the wave (tie -> smaller k)
#pragma unroll
  for (int pp = 0; pp < 8; ++pp) {
    double v = best[pp]; int k = bk[pp];
    for (int off = 32; off; off >>= 1) {
      const double ov = __shfl_xor(v, off);
      const int    ok = __shfl_xor(k, off);
      if (ov > v || (ov == v && ok < k)) { v = ov; k = ok; }
    }
    if (l == 0) {
      const int p = pbase + w * 8 + pp;
      trueCode[p] = k;
      atomicAdd(&binCnt[(p >> 12) * KK + k], 1);
    }
  }
}

// ---------------- per-row sampling: prob, masks, gumbel, code (partitionable PRNG) ----------------
__global__ __launch_bounds__(256) void k_final(const float* __restrict__ logit,
                                               const int* __restrict__ trueCode,
                                               const int* __restrict__ binCnt,
                                               float* __restrict__ out_code,
                                               float* __restrict__ out_tc,
                                               float* __restrict__ out_freq,
                                               int* __restrict__ code_int,
                                               uint32_t r1a, uint32_t r1b,
                                               uint32_t r2a, uint32_t r2b,
                                               uint32_t r3a, uint32_t r3b) {
  const int p = blockIdx.x;
  const int t = threadIdx.x;
  __shared__ float  redf[4];
  __shared__ double redd[4];
  __shared__ int    redi[4];

  const float4 L4 = *(const float4*)&logit[(size_t)p * KK + t * 4];
  const float l[4] = {L4.x, L4.y, L4.z, L4.w};

  // row max
  float m = fmaxf(fmaxf(l[0], l[1]), fmaxf(l[2], l[3]));
  for (int off = 32; off; off >>= 1) m = fmaxf(m, __shfl_xor(m, off));
  if ((t & 63) == 0) redf[t >> 6] = m;
  __syncthreads();
  m = fmaxf(fmaxf(redf[0], redf[1]), fmaxf(redf[2], redf[3]));

  // exp + sum (f64)
  double e[4], s = 0.0;
#pragma unroll
  for (int j = 0; j < 4; ++j) { e[j] = exp((double)l[j] - (double)m); s += e[j]; }
  for (int off = 32; off; off >>= 1) s += __shfl_xor(s, off);
  if ((t & 63) == 0) redd[t >> 6] = s;
  __syncthreads();
  s = redd[0] + redd[1] + redd[2] + redd[3];

  // row scalars: trueCode, frequency, dropout (partitionable bits: tf(key, 0, idx), b1^b2)
  const int tc = trueCode[p];
  const float fq = (float)binCnt[(p >> 12) * KK + tc];
  uint32_t d0, d1; tf2x32(r2a, r2b, 0u, (uint32_t)p, d0, d1);
  const bool drop = bits_to_u(d0 ^ d1) < fq * (1.0f / 4096.0f);

  // per-k mask + gumbel + argmax
  double bv = -1.0e300; int bk = 0;
#pragma unroll
  for (int j = 0; j < 4; ++j) {
    const int k = t * 4 + j;
    const uint32_t idx = (uint32_t)(p * KK + k);
    uint32_t m0, m1, g0, g1;
    tf2x32(r1a, r1b, 0u, idx, m0, m1);
    tf2x32(r3a, r3b, 0u, idx, g0, g1);
    double prob = e[j] / s; if (prob < 0.0009765625) prob = 0.0;
    const bool mk = ((double)bits_to_u(m0 ^ m1) < prob) || (k == tc && drop);
    const float u3 = fmaxf(bits_to_u(g0 ^ g1), 1.17549435082228751e-38f);
    const double g = -log(-log((double)u3));
    const double z = mk ? (g - 1.0e9) : ((double)l[j] + g);
    if (z > bv) { bv = z; bk = k; }
  }
  for (int off = 32; off; off >>= 1) {
    const double ov = __shfl_xor(bv, off);
    const int    ok = __shfl_xor(bk, off);
    if (ov > bv || (ov == bv && ok < bk)) { bv = ov; bk = ok; }
  }
  __syncthreads();   // redd/redi reuse
  if ((t & 63) == 0) { redd[t >> 6] = bv; redi[t >> 6] = bk; }
  __syncthreads();
  if (t == 0) {
    double v0 = redd[0]; int k0 = redi[0];
    for (int i = 1; i < 4; ++i)
      if (redd[i] > v0 || (redd[i] == v0 && redi[i] < k0)) { v0 = redd[i]; k0 = redi[i]; }
    out_code[p] = (float)k0; code_int[p] = k0;
    out_tc[p] = (float)tc;   out_freq[p] = fq;
  }
}

// ---------------- quantized[n][o][h][w] = v[code[n,h,w]][o] ----------------
__global__ __launch_bounds__(256) void k_quant(const float* __restrict__ v,
                                               const int* __restrict__ code_int,
                                               float* __restrict__ outq) {
  const int rb = blockIdx.x;           // n*64 + h
  const int n = rb >> 6, h = rb & 63;
  const int t = threadIdx.x;
  __shared__ int codes[64];
  if (t < 64) codes[t] = code_int[rb * 64 + t];
  __syncthreads();
  const int w = t & 63, og = t >> 6;
  const float* vr = v + (size_t)codes[w] * COUT;
  float* ob = outq + (size_t)n * COUT * 4096 + (size_t)h * 64 + w;
  for (int o = og * 128; o < og * 128 + 128; ++o)
    ob[(size_t)o * 4096] = vr[o];
}

__global__ __launch_bounds__(256) void k_bincopy(const int* __restrict__ binCnt,
                                                 float* __restrict__ outb) {
  const int i = blockIdx.x * 256 + threadIdx.x;
  if (i < NB * KK) outb[i] = (float)binCnt[i];
}

// ---------------- host launch ----------------
extern "C" void kernel_launch(void* const* d_in, const int* in_sizes, int n_in,
                              void* d_out, int out_size, void* d_ws, size_t ws_size,
                              hipStream_t stream) {
  const float* latent   = (const float*)d_in[0];
  const float* codebook = (const float*)d_in[1];
  const float* wq       = (const float*)d_in[2];
  const float* wk       = (const float*)d_in[3];
  const float* wv       = (const float*)d_in[4];
  // d_in[5] = temperature (==1); argmax is invariant to positive temperature -> ignored.

  float* out = (float*)d_out;
  float* out_quant = out;                          // 33,554,432
  float* out_code  = out + 33554432;               //     65,536
  float* out_logit = out + 33619968;               // 67,108,864
  float* out_tc    = out + 100728832;              //     65,536
  float* out_freq  = out + 100794368;              //     65,536
  float* out_bin   = out + 100859904;              //     16,384

  char* ws = (char*)d_ws;
  float* q        = (float*)(ws);                  // 134,217,728 B
  float* kmatT    = (float*)(ws + 134217728);      //   2,097,152 B
  float* v        = (float*)(ws + 136314880);      //   2,097,152 B
  int*   trueCode = (int*)  (ws + 138412032);      //     262,144 B
  int*   code_int = (int*)  (ws + 138674176);      //     262,144 B
  int*   binCnt   = (int*)  (ws + 138936320);      //      65,536 B

  // JAX partitionable PRNG: key(1234) = (0,1234).
  // split(key,3) foldlike: key_i = threefry2x32(key, x0=0, x1=i) -> (o0, o1).
  uint32_t r1a, r1b, r2a, r2b, r3a, r3b;
  tf2x32(0u, 1234u, 0u, 0u, r1a, r1b);   // r1: mask bernoulli
  tf2x32(0u, 1234u, 0u, 1u, r2a, r2b);   // r2: dropout
  tf2x32(0u, 1234u, 0u, 2u, r3a, r3b);   // r3: gumbel

  hipMemsetAsync(binCnt, 0, NB * KK * sizeof(int), stream);
  k_kmv   <<<1024,  256, 0, stream>>>(codebook, wk, wv, kmatT, v);
  k_q     <<<4096,  256, 0, stream>>>(latent, wq, q);
  k_logit <<<2048,  256, 0, stream>>>(q, kmatT, out_logit, trueCode, binCnt);
  k_final <<<65536, 256, 0, stream>>>(out_logit, trueCode, binCnt,
                                      out_code, out_tc, out_freq, code_int,
                                      r1a, r1b, r2a, r2b, r3a, r3b);
  k_quant <<<1024,  256, 0, stream>>>(v, code_int, out_quant);
  k_bincopy<<<64,   256, 0, stream>>>(binCnt, out_bin);
}

// Round 3
// 1778.689 us; speedup vs baseline: 2.1648x; 2.1648x over previous
//
#include <hip/hip_runtime.h>
#include <stdint.h>
#include <stddef.h>

#define NB   16
#define CIN  512
#define COUT 512
#define KK   1024

#define MARGIN    2e-5f
#define INV_SCALE 0.04419417382415922f   // 1/sqrt(512)

// ---------------- threefry2x32 (JAX-compatible, 20 rounds) ----------------
__host__ __device__ inline void tf2x32(uint32_t k0, uint32_t k1,
                                       uint32_t x0, uint32_t x1,
                                       uint32_t& o0, uint32_t& o1) {
  uint32_t ks2 = k0 ^ k1 ^ 0x1BD11BDAu;
  x0 += k0; x1 += k1;
#define TF_RND(r) { x0 += x1; x1 = (x1 << r) | (x1 >> (32 - r)); x1 ^= x0; }
  TF_RND(13) TF_RND(15) TF_RND(26) TF_RND(6)
  x0 += k1;  x1 += ks2 + 1u;
  TF_RND(17) TF_RND(29) TF_RND(16) TF_RND(24)
  x0 += ks2; x1 += k0 + 2u;
  TF_RND(13) TF_RND(15) TF_RND(26) TF_RND(6)
  x0 += k0;  x1 += k1 + 3u;
  TF_RND(17) TF_RND(29) TF_RND(16) TF_RND(24)
  x0 += k1;  x1 += ks2 + 4u;
  TF_RND(13) TF_RND(15) TF_RND(26) TF_RND(6)
  x0 += ks2; x1 += k0 + 5u;
#undef TF_RND
  o0 = x0; o1 = x1;
}

__device__ inline float bits_to_u(uint32_t b) {
  return __uint_as_float((b >> 9) | 0x3f800000u) - 1.0f;
}

// ---------------- kmatT64[o][k] (f64), v[k][o] = codebook @ wv^T (f32) ----------------
__global__ __launch_bounds__(256) void k_prep(const float* __restrict__ cb,
                                              const float* __restrict__ wk,
                                              const float* __restrict__ wv,
                                              double* __restrict__ kmatT64,
                                              float* __restrict__ v) {
  __shared__ __align__(16) float row[CIN];
  const int k = blockIdx.x;
  const int t = threadIdx.x;
  const float* cr = cb + (size_t)k * CIN;
  for (int c = t; c < CIN; c += 256) row[c] = cr[c];
  __syncthreads();
#pragma unroll
  for (int oo = 0; oo < 2; ++oo) {
    const int o = t + oo * 256;
    const float* kr = wk + (size_t)o * CIN;
    const float* vr = wv + (size_t)o * CIN;
    double ak = 0.0, av = 0.0;
    for (int c = 0; c < CIN; c += 4) {
      float4 c4 = *(const float4*)&row[c];
      float4 k4 = *(const float4*)(kr + c);
      float4 v4 = *(const float4*)(vr + c);
      ak += (double)c4.x * (double)k4.x; av += (double)c4.x * (double)v4.x;
      ak += (double)c4.y * (double)k4.y; av += (double)c4.y * (double)v4.y;
      ak += (double)c4.z * (double)k4.z; av += (double)c4.z * (double)v4.z;
      ak += (double)c4.w * (double)k4.w; av += (double)c4.w * (double)v4.w;
    }
    kmatT64[(size_t)o * KK + k] = ak;
    v[(size_t)k * COUT + o]    = (float)av;
  }
}

// ---------------- W[c][k] = sum_o wq[o][c] * kmat[k][o]  (f64; store f32 + f64^T) ----------------
__global__ __launch_bounds__(256) void k_wfold(const float* __restrict__ wq,
                                               const double* __restrict__ kmatT64,
                                               float* __restrict__ W32,
                                               double* __restrict__ WT64) {
  __shared__ __align__(16) float  As[16][64];    // [o][c]
  __shared__ __align__(16) double Bs[16][128];   // [o][k]
  const int t  = threadIdx.x;
  const int cb = (blockIdx.x >> 3) * 64;
  const int kb = (blockIdx.x & 7) * 128;
  const int tc = t >> 4, tk = t & 15;

  double acc[4][8];
#pragma unroll
  for (int i = 0; i < 4; ++i)
#pragma unroll
    for (int j = 0; j < 8; ++j) acc[i][j] = 0.0;

  for (int o0 = 0; o0 < COUT; o0 += 16) {
    {
      const int o2 = t >> 4, c4 = (t & 15) * 4;
      float4 f = *(const float4*)&wq[(size_t)(o0 + o2) * CIN + cb + c4];
      As[o2][c4+0] = f.x; As[o2][c4+1] = f.y; As[o2][c4+2] = f.z; As[o2][c4+3] = f.w;
    }
    {
      const int o2 = t >> 4, k8 = (t & 15) * 8;
      const double* src = &kmatT64[(size_t)(o0 + o2) * KK + kb + k8];
#pragma unroll
      for (int j = 0; j < 8; ++j) Bs[o2][k8 + j] = src[j];
    }
    __syncthreads();
#pragma unroll 4
    for (int o2 = 0; o2 < 16; ++o2) {
      double a[4], b[8];
#pragma unroll
      for (int i = 0; i < 4; ++i) a[i] = (double)As[o2][tc*4 + i];
#pragma unroll
      for (int j = 0; j < 8; ++j) b[j] = Bs[o2][tk*8 + j];
#pragma unroll
      for (int i = 0; i < 4; ++i)
#pragma unroll
        for (int j = 0; j < 8; ++j) acc[i][j] += a[i] * b[j];
    }
    __syncthreads();
  }
#pragma unroll
  for (int i = 0; i < 4; ++i) {
    const int c = cb + tc*4 + i;
#pragma unroll
    for (int j = 0; j < 8; ++j) {
      const int k = kb + tk*8 + j;
      W32 [(size_t)c * KK + k]  = (float)acc[i][j];
      WT64[(size_t)k * CIN + c] = acc[i][j];
    }
  }
}

// ---------------- logit = latent·W / sqrt(512)  (f32 GEMM + f64 candidate rescore) ----------------
__global__ __launch_bounds__(256) void k_logit(const float* __restrict__ latent,
                                               const float* __restrict__ W32,
                                               const double* __restrict__ WT64,
                                               float* __restrict__ out_logit,
                                               int* __restrict__ trueCode,
                                               int* __restrict__ binCnt) {
  __shared__ __align__(16) float As[16][64];    // [c][w]
  __shared__ __align__(16) float Bs[16][256];   // [c][k]
  __shared__ float rowmax[64];
  __shared__ int   rowargk[64];
  __shared__ int   candK[64][8];
  __shared__ int   candCnt[64];

  const int t  = threadIdx.x;
  const int rb = blockIdx.x;              // n*64 + h
  const int n  = rb >> 6, h = rb & 63;
  const int ki = t & 31, pi = t >> 5;

  const float* Ab = latent + (size_t)n * CIN * 4096 + h * 64;

  float best8[8]; int bk8[8];
#pragma unroll
  for (int i = 0; i < 8; ++i) { best8[i] = -1.0e30f; bk8[i] = 0; }

  for (int kc = 0; kc < 4; ++kc) {
    float acc[8][8] = {};
    for (int c0 = 0; c0 < CIN; c0 += 16) {
      {
        const int c2 = t >> 4, w4 = (t & 15) * 4;
        float4 f = *(const float4*)(Ab + (size_t)(c0 + c2) * 4096 + w4);
        *(float4*)&As[c2][w4] = f;
      }
      {
        const int c2 = t >> 4, k16 = (t & 15) * 16;
        const float* src = &W32[(size_t)(c0 + c2) * KK + kc * 256 + k16];
#pragma unroll
        for (int i = 0; i < 4; ++i)
          *(float4*)&Bs[c2][k16 + i*4] = *(const float4*)(src + i*4);
      }
      __syncthreads();
#pragma unroll 8
      for (int c = 0; c < 16; ++c) {
        const float4 A0 = *(const float4*)&As[c][pi*4];
        const float4 A1 = *(const float4*)&As[c][32 + pi*4];
        const float4 B0 = *(const float4*)&Bs[c][ki*4];
        const float4 B1 = *(const float4*)&Bs[c][128 + ki*4];
        const float ar[8] = {A0.x,A0.y,A0.z,A0.w,A1.x,A1.y,A1.z,A1.w};
        const float br[8] = {B0.x,B0.y,B0.z,B0.w,B1.x,B1.y,B1.z,B1.w};
#pragma unroll
        for (int i = 0; i < 8; ++i)
#pragma unroll
          for (int j = 0; j < 8; ++j)
            acc[i][j] += ar[i] * br[j];
      }
      __syncthreads();
    }
    // emit this kc chunk
#pragma unroll
    for (int i = 0; i < 8; ++i) {
      const int w = (i < 4) ? (pi*4 + i) : (32 + pi*4 + i - 4);
      const size_t base = (size_t)(rb*64 + w) * KK + kc * 256;
      float v0[4], v1[4];
#pragma unroll
      for (int j = 0; j < 4; ++j) { v0[j] = acc[i][j] * INV_SCALE; v1[j] = acc[i][4+j] * INV_SCALE; }
      *(float4*)&out_logit[base + ki*4]       = make_float4(v0[0], v0[1], v0[2], v0[3]);
      *(float4*)&out_logit[base + 128 + ki*4] = make_float4(v1[0], v1[1], v1[2], v1[3]);
#pragma unroll
      for (int j = 0; j < 4; ++j) {
        const int k0 = kc*256 + ki*4 + j;
        if (v0[j] > best8[i]) { best8[i] = v0[j]; bk8[i] = k0; }
      }
#pragma unroll
      for (int j = 0; j < 4; ++j) {
        const int k1 = kc*256 + 128 + ki*4 + j;
        if (v1[j] > best8[i]) { best8[i] = v1[j]; bk8[i] = k1; }
      }
    }
  }

  // reduce per-row max across the 32 ki-lanes
#pragma unroll
  for (int i = 0; i < 8; ++i) {
    float v = best8[i]; int k = bk8[i];
    for (int off = 16; off; off >>= 1) {
      const float ov = __shfl_xor(v, off);
      const int   ok = __shfl_xor(k, off);
      if (ov > v || (ov == v && ok < k)) { v = ov; k = ok; }
    }
    best8[i] = v; bk8[i] = k;
  }
  if (ki == 0) {
#pragma unroll
    for (int i = 0; i < 8; ++i) {
      const int w = (i < 4) ? (pi*4 + i) : (32 + pi*4 + i - 4);
      rowmax[w] = best8[i]; rowargk[w] = bk8[i];
    }
  }
  if (t < 64) candCnt[t] = 0;
  __syncthreads();

  // candidate scan: all k within MARGIN of the row's f32 max
  {
    const int r = t >> 2, qd = t & 3;
    const size_t base = (size_t)(rb*64 + r) * KK + qd * 256;
    const float thr = rowmax[r] - MARGIN;
    for (int x = 0; x < 64; ++x) {
      const float4 f = *(const float4*)&out_logit[base + x*4];
      const int kb = qd*256 + x*4;
      if (f.x >= thr) { int id = atomicAdd(&candCnt[r], 1); if (id < 8) candK[r][id] = kb + 0; }
      if (f.y >= thr) { int id = atomicAdd(&candCnt[r], 1); if (id < 8) candK[r][id] = kb + 1; }
      if (f.z >= thr) { int id = atomicAdd(&candCnt[r], 1); if (id < 8) candK[r][id] = kb + 2; }
      if (f.w >= thr) { int id = atomicAdd(&candCnt[r], 1); if (id < 8) candK[r][id] = kb + 3; }
    }
  }
  __syncthreads();

  // finalize: cnt==1 -> f32 argmax is exact enough; cnt>=2 -> f64 rescore (rare)
  const int wv = t >> 6, lane = t & 63;
  for (int rr = 0; rr < 16; ++rr) {
    const int r = wv*16 + rr;
    const int p = rb*64 + r;
    int cnt = candCnt[r]; if (cnt > 8) cnt = 8;
    if (cnt <= 1) {
      if (lane == 0) {
        const int tc0 = rowargk[r];
        trueCode[p] = tc0;
        atomicAdd(&binCnt[n * KK + tc0], 1);
      }
    } else {
      int ks[8];
#pragma unroll
      for (int m = 0; m < 8; ++m) ks[m] = candK[r][m < cnt ? m : 0];
      double part[8] = {0,0,0,0,0,0,0,0};
#pragma unroll
      for (int jj = 0; jj < 8; ++jj) {
        const int c = jj*64 + lane;
        const double lv = (double)Ab[(size_t)c * 4096 + r];
#pragma unroll
        for (int m = 0; m < 8; ++m)
          if (m < cnt) part[m] += lv * WT64[(size_t)ks[m] * CIN + c];
      }
#pragma unroll
      for (int m = 0; m < 8; ++m)
        for (int off = 32; off; off >>= 1) part[m] += __shfl_xor(part[m], off);
      if (lane == 0) {
        double bv = -1.0e300; int bkk = KK;
#pragma unroll
        for (int m = 0; m < 8; ++m)
          if (m < cnt && (part[m] > bv || (part[m] == bv && ks[m] < bkk))) { bv = part[m]; bkk = ks[m]; }
        trueCode[p] = bkk;
        atomicAdd(&binCnt[n * KK + bkk], 1);
      }
    }
  }
}

// ---------------- per-row sampling: prob (f64, as round 2), gumbel (f32), code ----------------
__global__ __launch_bounds__(256) void k_final(const float* __restrict__ logit,
                                               const int* __restrict__ trueCode,
                                               const int* __restrict__ binCnt,
                                               float* __restrict__ out_code,
                                               float* __restrict__ out_tc,
                                               float* __restrict__ out_freq,
                                               int* __restrict__ code_int,
                                               uint32_t r1a, uint32_t r1b,
                                               uint32_t r2a, uint32_t r2b,
                                               uint32_t r3a, uint32_t r3b) {
  const int p = blockIdx.x;
  const int t = threadIdx.x;
  __shared__ float  redf[4];
  __shared__ double redd[4];
  __shared__ float  redz[4];
  __shared__ int    redi[4];

  const float4 L4 = *(const float4*)&logit[(size_t)p * KK + t * 4];
  const float l[4] = {L4.x, L4.y, L4.z, L4.w};

  float m = fmaxf(fmaxf(l[0], l[1]), fmaxf(l[2], l[3]));
  for (int off = 32; off; off >>= 1) m = fmaxf(m, __shfl_xor(m, off));
  if ((t & 63) == 0) redf[t >> 6] = m;
  __syncthreads();
  m = fmaxf(fmaxf(redf[0], redf[1]), fmaxf(redf[2], redf[3]));

  double e[4], s = 0.0;
#pragma unroll
  for (int j = 0; j < 4; ++j) { e[j] = exp((double)l[j] - (double)m); s += e[j]; }
  for (int off = 32; off; off >>= 1) s += __shfl_xor(s, off);
  if ((t & 63) == 0) redd[t >> 6] = s;
  __syncthreads();
  s = redd[0] + redd[1] + redd[2] + redd[3];

  const int tc = trueCode[p];
  const float fq = (float)binCnt[(p >> 12) * KK + tc];
  uint32_t d0, d1; tf2x32(r2a, r2b, 0u, (uint32_t)p, d0, d1);
  const bool drop = bits_to_u(d0 ^ d1) < fq * (1.0f / 4096.0f);

  float bv = -3.0e38f; int bk = 0;
#pragma unroll
  for (int j = 0; j < 4; ++j) {
    const int k = t * 4 + j;
    const uint32_t idx = (uint32_t)(p * KK + k);
    uint32_t m0, m1, g0, g1;
    tf2x32(r1a, r1b, 0u, idx, m0, m1);
    tf2x32(r3a, r3b, 0u, idx, g0, g1);
    double prob = e[j] / s; if (prob < 0.0009765625) prob = 0.0;
    const bool mk = ((double)bits_to_u(m0 ^ m1) < prob) || (k == tc && drop);
    const float u3  = fmaxf(bits_to_u(g0 ^ g1), 1.17549435082228751e-38f);
    const float gum = -logf(-logf(u3));
    const float z = mk ? (gum - 1.0e9f) : (l[j] + gum);
    if (z > bv) { bv = z; bk = k; }
  }
  for (int off = 32; off; off >>= 1) {
    const float ov = __shfl_xor(bv, off);
    const int   ok = __shfl_xor(bk, off);
    if (ov > bv || (ov == bv && ok < bk)) { bv = ov; bk = ok; }
  }
  __syncthreads();
  if ((t & 63) == 0) { redz[t >> 6] = bv; redi[t >> 6] = bk; }
  __syncthreads();
  if (t == 0) {
    float v0 = redz[0]; int k0 = redi[0];
    for (int i = 1; i < 4; ++i)
      if (redz[i] > v0 || (redz[i] == v0 && redi[i] < k0)) { v0 = redz[i]; k0 = redi[i]; }
    out_code[p] = (float)k0; code_int[p] = k0;
    out_tc[p] = (float)tc;   out_freq[p] = fq;
  }
}

// ---------------- quantized[n][o][h][w] = v[code[n,h,w]][o] ----------------
__global__ __launch_bounds__(256) void k_quant(const float* __restrict__ v,
                                               const int* __restrict__ code_int,
                                               float* __restrict__ outq) {
  const int rb = blockIdx.x;
  const int n = rb >> 6, h = rb & 63;
  const int t = threadIdx.x;
  __shared__ int codes[64];
  if (t < 64) codes[t] = code_int[rb * 64 + t];
  __syncthreads();
  const int w = t & 63, og = t >> 6;
  const float* vr = v + (size_t)codes[w] * COUT;
  float* ob = outq + (size_t)n * COUT * 4096 + (size_t)h * 64 + w;
  for (int o = og * 128; o < og * 128 + 128; ++o)
    ob[(size_t)o * 4096] = vr[o];
}

__global__ __launch_bounds__(256) void k_bincopy(const int* __restrict__ binCnt,
                                                 float* __restrict__ outb) {
  const int i = blockIdx.x * 256 + threadIdx.x;
  if (i < NB * KK) outb[i] = (float)binCnt[i];
}

// ---------------- host launch ----------------
extern "C" void kernel_launch(void* const* d_in, const int* in_sizes, int n_in,
                              void* d_out, int out_size, void* d_ws, size_t ws_size,
                              hipStream_t stream) {
  const float* latent   = (const float*)d_in[0];
  const float* codebook = (const float*)d_in[1];
  const float* wq       = (const float*)d_in[2];
  const float* wk       = (const float*)d_in[3];
  const float* wv       = (const float*)d_in[4];

  float* out = (float*)d_out;
  float* out_quant = out;                          // 33,554,432
  float* out_code  = out + 33554432;               //     65,536
  float* out_logit = out + 33619968;               // 67,108,864
  float* out_tc    = out + 100728832;              //     65,536
  float* out_freq  = out + 100794368;              //     65,536
  float* out_bin   = out + 100859904;              //     16,384

  char* ws = (char*)d_ws;
  double* kmatT64 = (double*)(ws);                 // 4 MiB
  double* WT64    = (double*)(ws + (4u<<20));      // 4 MiB
  float*  W32     = (float*) (ws + (8u<<20));      // 2 MiB
  float*  v       = (float*) (ws + (10u<<20));     // 2 MiB
  int*    trueCode= (int*)   (ws + (12u<<20));     // 256 KiB
  int*    code_int= (int*)   (ws + (12u<<20) + 262144);
  int*    binCnt  = (int*)   (ws + (12u<<20) + 524288);

  // JAX partitionable PRNG: key(1234) = (0,1234); split foldlike.
  uint32_t r1a, r1b, r2a, r2b, r3a, r3b;
  tf2x32(0u, 1234u, 0u, 0u, r1a, r1b);   // r1: mask bernoulli
  tf2x32(0u, 1234u, 0u, 1u, r2a, r2b);   // r2: dropout
  tf2x32(0u, 1234u, 0u, 2u, r3a, r3b);   // r3: gumbel

  hipMemsetAsync(binCnt, 0, NB * KK * sizeof(int), stream);
  k_prep  <<<1024,  256, 0, stream>>>(codebook, wk, wv, kmatT64, v);
  k_wfold <<<64,    256, 0, stream>>>(wq, kmatT64, W32, WT64);
  k_logit <<<1024,  256, 0, stream>>>(latent, W32, WT64, out_logit, trueCode, binCnt);
  k_final <<<65536, 256, 0, stream>>>(out_logit, trueCode, binCnt,
                                      out_code, out_tc, out_freq, code_int,
                                      r1a, r1b, r2a, r2b, r3a, r3b);
  k_quant <<<1024,  256, 0, stream>>>(v, code_int, out_quant);
  k_bincopy<<<64,   256, 0, stream>>>(binCnt, out_bin);
}

// Round 4
// 1345.333 us; speedup vs baseline: 2.8622x; 1.3221x over previous
//
#include <hip/hip_runtime.h>
#include <stdint.h>
#include <stddef.h>

#define NB   16
#define CIN  512
#define COUT 512
#define KK   1024

#define MARGIN    2e-5f
#define INV_SCALE 0.04419417382415922f   // 1/sqrt(512)

typedef short short4v __attribute__((ext_vector_type(4)));
typedef short short8v __attribute__((ext_vector_type(8)));
typedef float f32x4  __attribute__((ext_vector_type(4)));

union Frag { short4v h[2]; short8v v8; };

// ---------------- threefry2x32 (JAX-compatible, 20 rounds) ----------------
__host__ __device__ inline void tf2x32(uint32_t k0, uint32_t k1,
                                       uint32_t x0, uint32_t x1,
                                       uint32_t& o0, uint32_t& o1) {
  uint32_t ks2 = k0 ^ k1 ^ 0x1BD11BDAu;
  x0 += k0; x1 += k1;
#define TF_RND(r) { x0 += x1; x1 = (x1 << r) | (x1 >> (32 - r)); x1 ^= x0; }
  TF_RND(13) TF_RND(15) TF_RND(26) TF_RND(6)
  x0 += k1;  x1 += ks2 + 1u;
  TF_RND(17) TF_RND(29) TF_RND(16) TF_RND(24)
  x0 += ks2; x1 += k0 + 2u;
  TF_RND(13) TF_RND(15) TF_RND(26) TF_RND(6)
  x0 += k0;  x1 += k1 + 3u;
  TF_RND(17) TF_RND(29) TF_RND(16) TF_RND(24)
  x0 += k1;  x1 += ks2 + 4u;
  TF_RND(13) TF_RND(15) TF_RND(26) TF_RND(6)
  x0 += ks2; x1 += k0 + 5u;
#undef TF_RND
  o0 = x0; o1 = x1;
}

__device__ inline float bits_to_u(uint32_t b) {
  return __uint_as_float((b >> 9) | 0x3f800000u) - 1.0f;
}

__device__ __host__ inline uint16_t f2bf(float f) {
  union { float f; uint32_t u; } c; c.f = f;
  uint32_t r = (c.u + 0x7fffu + ((c.u >> 16) & 1u)) >> 16;
  return (uint16_t)r;
}
__device__ inline float bf2f(uint16_t h) {
  union { uint32_t u; float f; } c; c.u = ((uint32_t)h) << 16;
  return c.f;
}

// ---------------- kmatT64[o][k] (f64), v[k][o] = codebook @ wv^T (f32) ----------------
__global__ __launch_bounds__(256) void k_prep(const float* __restrict__ cb,
                                              const float* __restrict__ wk,
                                              const float* __restrict__ wv,
                                              double* __restrict__ kmatT64,
                                              float* __restrict__ v) {
  __shared__ __align__(16) float row[CIN];
  const int k = blockIdx.x;
  const int t = threadIdx.x;
  const float* cr = cb + (size_t)k * CIN;
  for (int c = t; c < CIN; c += 256) row[c] = cr[c];
  __syncthreads();
#pragma unroll
  for (int oo = 0; oo < 2; ++oo) {
    const int o = t + oo * 256;
    const float* kr = wk + (size_t)o * CIN;
    const float* vr = wv + (size_t)o * CIN;
    double ak = 0.0, av = 0.0;
    for (int c = 0; c < CIN; c += 4) {
      float4 c4 = *(const float4*)&row[c];
      float4 k4 = *(const float4*)(kr + c);
      float4 v4 = *(const float4*)(vr + c);
      ak += (double)c4.x * (double)k4.x; av += (double)c4.x * (double)v4.x;
      ak += (double)c4.y * (double)k4.y; av += (double)c4.y * (double)v4.y;
      ak += (double)c4.z * (double)k4.z; av += (double)c4.z * (double)v4.z;
      ak += (double)c4.w * (double)k4.w; av += (double)c4.w * (double)v4.w;
    }
    kmatT64[(size_t)o * KK + k] = ak;
    v[(size_t)k * COUT + o]    = (float)av;
  }
}

// ---- W[c][k] = sum_o wq[o][c]*kmat[k][o]; emit WT64[k][c] f64 + Wt hi/lo bf16 [k][c] ----
__global__ __launch_bounds__(256) void k_wfold(const float* __restrict__ wq,
                                               const double* __restrict__ kmatT64,
                                               double* __restrict__ WT64,
                                               uint16_t* __restrict__ Wth,
                                               uint16_t* __restrict__ Wtl) {
  __shared__ __align__(16) float  As[16][64];    // [o][c]
  __shared__ __align__(16) double Bs[16][128];   // [o][k]
  const int t  = threadIdx.x;
  const int cb = (blockIdx.x >> 3) * 64;
  const int kb = (blockIdx.x & 7) * 128;
  const int tc = t >> 4, tk = t & 15;

  double acc[4][8];
#pragma unroll
  for (int i = 0; i < 4; ++i)
#pragma unroll
    for (int j = 0; j < 8; ++j) acc[i][j] = 0.0;

  for (int o0 = 0; o0 < COUT; o0 += 16) {
    {
      const int o2 = t >> 4, c4 = (t & 15) * 4;
      float4 f = *(const float4*)&wq[(size_t)(o0 + o2) * CIN + cb + c4];
      As[o2][c4+0] = f.x; As[o2][c4+1] = f.y; As[o2][c4+2] = f.z; As[o2][c4+3] = f.w;
    }
    {
      const int o2 = t >> 4, k8 = (t & 15) * 8;
      const double* src = &kmatT64[(size_t)(o0 + o2) * KK + kb + k8];
#pragma unroll
      for (int j = 0; j < 8; ++j) Bs[o2][k8 + j] = src[j];
    }
    __syncthreads();
#pragma unroll 4
    for (int o2 = 0; o2 < 16; ++o2) {
      double a[4], b[8];
#pragma unroll
      for (int i = 0; i < 4; ++i) a[i] = (double)As[o2][tc*4 + i];
#pragma unroll
      for (int j = 0; j < 8; ++j) b[j] = Bs[o2][tk*8 + j];
#pragma unroll
      for (int i = 0; i < 4; ++i)
#pragma unroll
        for (int j = 0; j < 8; ++j) acc[i][j] += a[i] * b[j];
    }
    __syncthreads();
  }
#pragma unroll
  for (int i = 0; i < 4; ++i) {
    const int c = cb + tc*4 + i;
#pragma unroll
    for (int j = 0; j < 8; ++j) {
      const int k = kb + tk*8 + j;
      const double a = acc[i][j];
      WT64[(size_t)k * CIN + c] = a;
      const float wf = (float)a;
      const uint16_t hb = f2bf(wf);
      const float lof = wf - bf2f(hb);
      Wth[(size_t)k * CIN + c] = hb;
      Wtl[(size_t)k * CIN + c] = f2bf(lof);
    }
  }
}

// ---------------- latent NCHW f32 -> A[p][c] bf16 hi/lo ----------------
__global__ __launch_bounds__(256) void k_aprep(const float* __restrict__ latent,
                                               uint16_t* __restrict__ Ahi,
                                               uint16_t* __restrict__ Alo) {
  __shared__ float T[128][68];
  const int rb = blockIdx.x, n = rb >> 6, h = rb & 63, t = threadIdx.x;
  for (int c0 = 0; c0 < 512; c0 += 128) {
    const int c2 = t >> 1, wh = (t & 1) * 32;
    const float* src = latent + (size_t)n * 2097152 + (size_t)(c0 + c2) * 4096 + h * 64 + wh;
#pragma unroll
    for (int i = 0; i < 8; ++i)
      *(float4*)&T[c2][wh + i*4] = *(const float4*)(src + i*4);
    __syncthreads();
    const int w = t & 63, cp = t >> 6;
    const size_t pr = (size_t)(rb * 64 + w) * 512 + c0 + cp * 32;
#pragma unroll
    for (int blk = 0; blk < 4; ++blk) {
      short8v hv, lv;
#pragma unroll
      for (int j = 0; j < 8; ++j) {
        const float f = T[cp*32 + blk*8 + j][w];
        const uint16_t hb = f2bf(f);
        const float lof = f - bf2f(hb);
        hv[j] = (short)hb; lv[j] = (short)f2bf(lof);
      }
      *(short8v*)(Ahi + pr + blk*8) = hv;
      *(short8v*)(Alo + pr + blk*8) = lv;
    }
    __syncthreads();
  }
}

// ---------------- logit GEMM: bf16x3 MFMA + fused argmax/rescore/binCount ----------------
__global__ __launch_bounds__(256, 2) void k_logit(
    const uint16_t* __restrict__ Ahi, const uint16_t* __restrict__ Alo,
    const uint16_t* __restrict__ Wth, const uint16_t* __restrict__ Wtl,
    const float* __restrict__ latent, const double* __restrict__ WT64,
    float* __restrict__ out_logit, int* __restrict__ trueCode, int* __restrict__ binCnt) {
  __shared__ uint16_t Bh[16384], Bl[16384];  // [kcol 256][c 64] swizzled, 32 KB each
  __shared__ float rowmax[64];
  __shared__ int   rowargk[64], candCnt[64], candK[64][8];

  const int t = threadIdx.x;
  const int wave = t >> 6, lane = t & 63;
  const int wr = wave >> 1, wc = wave & 1;
  const int rb = blockIdx.x, n = rb >> 6, h = rb & 63;
  const int pbase = rb * 64;
  const int lg = lane >> 4, l15 = lane & 15;

  for (int kc = 0; kc < 4; ++kc) {
    f32x4 acc[2][8];
#pragma unroll
    for (int rt = 0; rt < 2; ++rt)
#pragma unroll
      for (int ct = 0; ct < 8; ++ct) acc[rt][ct] = (f32x4){0.f, 0.f, 0.f, 0.f};

    for (int cst = 0; cst < 8; ++cst) {
      // stage B (hi/lo) with slot swizzle: stored byte = kcol*128 + ((c>>3)^(kcol&7))*16 + (c&7)*2
      {
        const int kbase = kc * 256, c0 = cst * 64;
#pragma unroll
        for (int i = 0; i < 8; ++i) {
          const int D = wave * 8192 + i * 1024 + lane * 16;
          const int kcol = D >> 7;
          const int s = (lane & 7) ^ (kcol & 7);
          const size_t off = (size_t)(kbase + kcol) * 512 + c0 + s * 8;
          *(short8v*)((char*)Bh + D) = *(const short8v*)(Wth + off);
          *(short8v*)((char*)Bl + D) = *(const short8v*)(Wtl + off);
        }
      }
      __syncthreads();
#pragma unroll
      for (int ks = 0; ks < 2; ++ks) {
        const int cA = cst * 64 + ks * 32 + 4 * lg;
        Frag ah[2], al[2];
#pragma unroll
        for (int rt = 0; rt < 2; ++rt) {
          const size_t rowoff = (size_t)(pbase + wr * 32 + rt * 16 + l15) * 512;
          ah[rt].h[0] = *(const short4v*)(Ahi + rowoff + cA);
          ah[rt].h[1] = *(const short4v*)(Ahi + rowoff + cA + 16);
          al[rt].h[0] = *(const short4v*)(Alo + rowoff + cA);
          al[rt].h[1] = *(const short4v*)(Alo + rowoff + cA + 16);
        }
#pragma unroll
        for (int ct = 0; ct < 8; ++ct) {
          const int kcol = wc * 128 + ct * 16 + l15;
          const int rowb = kcol * 128 + (lg & 1) * 8;
          const int x = kcol & 7;
          const int sA = (4 * ks + (lg >> 1)) ^ x;
          const int sB = (4 * ks + 2 + (lg >> 1)) ^ x;
          Frag bh, bl;
          bh.h[0] = *(const short4v*)((char*)Bh + rowb + (sA << 4));
          bh.h[1] = *(const short4v*)((char*)Bh + rowb + (sB << 4));
          bl.h[0] = *(const short4v*)((char*)Bl + rowb + (sA << 4));
          bl.h[1] = *(const short4v*)((char*)Bl + rowb + (sB << 4));
#pragma unroll
          for (int rt = 0; rt < 2; ++rt) {
            acc[rt][ct] = __builtin_amdgcn_mfma_f32_16x16x32_bf16(ah[rt].v8, bh.v8, acc[rt][ct], 0, 0, 0);
            acc[rt][ct] = __builtin_amdgcn_mfma_f32_16x16x32_bf16(ah[rt].v8, bl.v8, acc[rt][ct], 0, 0, 0);
            acc[rt][ct] = __builtin_amdgcn_mfma_f32_16x16x32_bf16(al[rt].v8, bh.v8, acc[rt][ct], 0, 0, 0);
          }
        }
      }
      __syncthreads();
    }
    // epilogue: scale + write (C: col = lane&15, row = 4*(lane>>4)+reg)
#pragma unroll
    for (int rt = 0; rt < 2; ++rt) {
#pragma unroll
      for (int reg = 0; reg < 4; ++reg) {
        const int prow = pbase + wr * 32 + rt * 16 + 4 * lg + reg;
        float* dst = out_logit + (size_t)prow * KK + kc * 256 + wc * 128 + l15;
#pragma unroll
        for (int ct = 0; ct < 8; ++ct)
          dst[ct * 16] = acc[rt][ct][reg] * INV_SCALE;
      }
    }
  }
  __syncthreads();

  // pass 1: per-row f32 max + argmax (tie -> smaller k)
  {
    const int r = t >> 2, qd = t & 3;
    const float* src = out_logit + (size_t)(pbase + r) * KK + qd * 256;
    float bv = -1.0e30f; int bk = 0;
    for (int x = 0; x < 64; ++x) {
      const float4 f = *(const float4*)(src + x * 4);
      const int kb = qd * 256 + x * 4;
      if (f.x > bv) { bv = f.x; bk = kb + 0; }
      if (f.y > bv) { bv = f.y; bk = kb + 1; }
      if (f.z > bv) { bv = f.z; bk = kb + 2; }
      if (f.w > bv) { bv = f.w; bk = kb + 3; }
    }
    for (int off = 1; off < 4; off <<= 1) {
      const float ov = __shfl_xor(bv, off);
      const int   ok = __shfl_xor(bk, off);
      if (ov > bv || (ov == bv && ok < bk)) { bv = ov; bk = ok; }
    }
    if (qd == 0) { rowmax[r] = bv; rowargk[r] = bk; }
    if (t < 64) candCnt[t] = 0;
  }
  __syncthreads();

  // pass 2: candidates within MARGIN of row max
  {
    const int r = t >> 2, qd = t & 3;
    const size_t base = (size_t)(pbase + r) * KK + qd * 256;
    const float thr = rowmax[r] - MARGIN;
    for (int x = 0; x < 64; ++x) {
      const float4 f = *(const float4*)&out_logit[base + x * 4];
      const int kb = qd * 256 + x * 4;
      if (f.x >= thr) { int id = atomicAdd(&candCnt[r], 1); if (id < 8) candK[r][id] = kb + 0; }
      if (f.y >= thr) { int id = atomicAdd(&candCnt[r], 1); if (id < 8) candK[r][id] = kb + 1; }
      if (f.z >= thr) { int id = atomicAdd(&candCnt[r], 1); if (id < 8) candK[r][id] = kb + 2; }
      if (f.w >= thr) { int id = atomicAdd(&candCnt[r], 1); if (id < 8) candK[r][id] = kb + 3; }
    }
  }
  __syncthreads();

  // finalize: cnt==1 -> f32 argmax exact enough; cnt>=2 -> f64 rescore (rare)
  const float* Ab = latent + (size_t)n * CIN * 4096 + h * 64;
  const int wv = t >> 6, lane_ = t & 63;
  for (int rr = 0; rr < 16; ++rr) {
    const int r = wv * 16 + rr;
    const int p = pbase + r;
    int cnt = candCnt[r]; if (cnt > 8) cnt = 8;
    if (cnt <= 1) {
      if (lane_ == 0) {
        const int tc0 = rowargk[r];
        trueCode[p] = tc0;
        atomicAdd(&binCnt[n * KK + tc0], 1);
      }
    } else {
      int ks[8];
#pragma unroll
      for (int m = 0; m < 8; ++m) ks[m] = candK[r][m < cnt ? m : 0];
      double part[8] = {0, 0, 0, 0, 0, 0, 0, 0};
#pragma unroll
      for (int jj = 0; jj < 8; ++jj) {
        const int c = jj * 64 + lane_;
        const double lv = (double)Ab[(size_t)c * 4096 + r];
#pragma unroll
        for (int m = 0; m < 8; ++m)
          if (m < cnt) part[m] += lv * WT64[(size_t)ks[m] * CIN + c];
      }
#pragma unroll
      for (int m = 0; m < 8; ++m)
        for (int off = 32; off; off >>= 1) part[m] += __shfl_xor(part[m], off);
      if (lane_ == 0) {
        double bv = -1.0e300; int bkk = KK;
#pragma unroll
        for (int m = 0; m < 8; ++m)
          if (m < cnt && (part[m] > bv || (part[m] == bv && ks[m] < bkk))) { bv = part[m]; bkk = ks[m]; }
        trueCode[p] = bkk;
        atomicAdd(&binCnt[n * KK + bkk], 1);
      }
    }
  }
}

// ---------------- per-row sampling: f32 softmax, threefry masks, gumbel, code ----------------
__global__ __launch_bounds__(256) void k_final(const float* __restrict__ logit,
                                               const int* __restrict__ trueCode,
                                               const int* __restrict__ binCnt,
                                               float* __restrict__ out_code,
                                               float* __restrict__ out_tc,
                                               float* __restrict__ out_freq,
                                               int* __restrict__ code_int,
                                               uint32_t r1a, uint32_t r1b,
                                               uint32_t r2a, uint32_t r2b,
                                               uint32_t r3a, uint32_t r3b) {
  const int p = blockIdx.x;
  const int t = threadIdx.x;
  __shared__ float redf[4], reds[4], redz[4];
  __shared__ int   redi[4];

  const float4 L4 = *(const float4*)&logit[(size_t)p * KK + t * 4];
  const float l[4] = {L4.x, L4.y, L4.z, L4.w};

  float m = fmaxf(fmaxf(l[0], l[1]), fmaxf(l[2], l[3]));
  for (int off = 32; off; off >>= 1) m = fmaxf(m, __shfl_xor(m, off));
  if ((t & 63) == 0) redf[t >> 6] = m;
  __syncthreads();
  m = fmaxf(fmaxf(redf[0], redf[1]), fmaxf(redf[2], redf[3]));

  float e[4], s = 0.f;
#pragma unroll
  for (int j = 0; j < 4; ++j) { e[j] = expf(l[j] - m); s += e[j]; }
  for (int off = 32; off; off >>= 1) s += __shfl_xor(s, off);
  if ((t & 63) == 0) reds[t >> 6] = s;
  __syncthreads();
  s = reds[0] + reds[1] + reds[2] + reds[3];

  const int tc = trueCode[p];
  const float fq = (float)binCnt[(p >> 12) * KK + tc];
  uint32_t d0, d1; tf2x32(r2a, r2b, 0u, (uint32_t)p, d0, d1);
  const bool drop = bits_to_u(d0 ^ d1) < fq * (1.0f / 4096.0f);

  const float thr = s * 0.0009765625f;  // s * 2^-10 (exact)
  float bv = -3.0e38f; int bk = 0;
#pragma unroll
  for (int j = 0; j < 4; ++j) {
    const int k = t * 4 + j;
    const uint32_t idx = (uint32_t)(p * KK + k);
    uint32_t m0, m1, g0, g1;
    tf2x32(r1a, r1b, 0u, idx, m0, m1);
    tf2x32(r3a, r3b, 0u, idx, g0, g1);
    const bool nz = e[j] >= thr;                 // prob >= 1/kk
    const bool mk = (nz && (bits_to_u(m0 ^ m1) * s < e[j])) || (k == tc && drop);
    const float u3  = fmaxf(bits_to_u(g0 ^ g1), 1.17549435082228751e-38f);
    const float gum = -logf(-logf(u3));
    const float z = mk ? (gum - 1.0e9f) : (l[j] + gum);
    if (z > bv) { bv = z; bk = k; }
  }
  for (int off = 32; off; off >>= 1) {
    const float ov = __shfl_xor(bv, off);
    const int   ok = __shfl_xor(bk, off);
    if (ov > bv || (ov == bv && ok < bk)) { bv = ov; bk = ok; }
  }
  __syncthreads();
  if ((t & 63) == 0) { redz[t >> 6] = bv; redi[t >> 6] = bk; }
  __syncthreads();
  if (t == 0) {
    float v0 = redz[0]; int k0 = redi[0];
    for (int i = 1; i < 4; ++i)
      if (redz[i] > v0 || (redz[i] == v0 && redi[i] < k0)) { v0 = redz[i]; k0 = redi[i]; }
    out_code[p] = (float)k0; code_int[p] = k0;
    out_tc[p] = (float)tc;   out_freq[p] = fq;
  }
}

// ---------------- quantized[n][o][h][w] = v[code[n,h,w]][o] ----------------
__global__ __launch_bounds__(256) void k_quant(const float* __restrict__ v,
                                               const int* __restrict__ code_int,
                                               float* __restrict__ outq) {
  const int rb = blockIdx.x;
  const int n = rb >> 6, h = rb & 63;
  const int t = threadIdx.x;
  __shared__ int codes[64];
  if (t < 64) codes[t] = code_int[rb * 64 + t];
  __syncthreads();
  const int w = t & 63, og = t >> 6;
  const float* vr = v + (size_t)codes[w] * COUT;
  float* ob = outq + (size_t)n * COUT * 4096 + (size_t)h * 64 + w;
  for (int o = og * 128; o < og * 128 + 128; ++o)
    ob[(size_t)o * 4096] = vr[o];
}

__global__ __launch_bounds__(256) void k_bincopy(const int* __restrict__ binCnt,
                                                 float* __restrict__ outb) {
  const int i = blockIdx.x * 256 + threadIdx.x;
  if (i < NB * KK) outb[i] = (float)binCnt[i];
}

// ---------------- host launch ----------------
extern "C" void kernel_launch(void* const* d_in, const int* in_sizes, int n_in,
                              void* d_out, int out_size, void* d_ws, size_t ws_size,
                              hipStream_t stream) {
  const float* latent   = (const float*)d_in[0];
  const float* codebook = (const float*)d_in[1];
  const float* wq       = (const float*)d_in[2];
  const float* wk       = (const float*)d_in[3];
  const float* wv       = (const float*)d_in[4];

  float* out = (float*)d_out;
  float* out_quant = out;                          // 33,554,432 f32 (128 MiB)
  float* out_code  = out + 33554432;
  float* out_logit = out + 33619968;
  float* out_tc    = out + 100728832;
  float* out_freq  = out + 100794368;
  float* out_bin   = out + 100859904;

  // W-scratch lives inside out_quant (fully overwritten by k_quant at the end):
  double*   WT64 = (double*)  out_quant;                 // 4 MiB
  uint16_t* Wth  = (uint16_t*)(out_quant + 1048576);     // 1 MiB
  uint16_t* Wtl  = (uint16_t*)(out_quant + 1572864);     // 1 MiB

  char* ws = (char*)d_ws;
  uint16_t* Ahi     = (uint16_t*)(ws);                   // 64 MiB  [0, 67108864)
  uint16_t* Alo     = (uint16_t*)(ws + 67108864);        // 64 MiB
  double*   kmatT64 = (double*)(ws);                     // 4 MiB, aliases Ahi head (dead before k_aprep)
  float*    v       = (float*)(ws + 134217728);          // 2 MiB
  int*      trueCode= (int*)  (ws + 136314880);
  int*      code_int= (int*)  (ws + 136577024);
  int*      binCnt  = (int*)  (ws + 136839168);

  // JAX partitionable PRNG: key(1234) = (0,1234); split foldlike.
  uint32_t r1a, r1b, r2a, r2b, r3a, r3b;
  tf2x32(0u, 1234u, 0u, 0u, r1a, r1b);   // r1: mask bernoulli
  tf2x32(0u, 1234u, 0u, 1u, r2a, r2b);   // r2: dropout
  tf2x32(0u, 1234u, 0u, 2u, r3a, r3b);   // r3: gumbel

  hipMemsetAsync(binCnt, 0, NB * KK * sizeof(int), stream);
  k_prep  <<<1024,  256, 0, stream>>>(codebook, wk, wv, kmatT64, v);
  k_wfold <<<64,    256, 0, stream>>>(wq, kmatT64, WT64, Wth, Wtl);
  k_aprep <<<1024,  256, 0, stream>>>(latent, Ahi, Alo);   // after k_wfold: overwrites kmatT64 alias
  k_logit <<<1024,  256, 0, stream>>>(Ahi, Alo, Wth, Wtl, latent, WT64,
                                      out_logit, trueCode, binCnt);
  k_final <<<65536, 256, 0, stream>>>(out_logit, trueCode, binCnt,
                                      out_code, out_tc, out_freq, code_int,
                                      r1a, r1b, r2a, r2b, r3a, r3b);
  k_quant <<<1024,  256, 0, stream>>>(v, code_int, out_quant);
  k_bincopy<<<64,   256, 0, stream>>>(binCnt, out_bin);
}